// Round 2
// baseline (1613.047 us; speedup 1.0000x reference)
//
#include <hip/hip_runtime.h>
#include <math.h>

namespace {

constexpr int kB  = 2;
constexpr int kL  = 8192;
constexpr int kD  = 768;
constexpr int kTD = 2304;  // 3*D

// ---------------- K1: qkv projection, split outputs ----------------
// q  [B][L][D]   (cols 0..767)
// kv [B][L][2D]  (cols 768..2303)
__global__ __launch_bounds__(256) void sgemm_qkv(
    const float* __restrict__ A, const float* __restrict__ W,
    float* __restrict__ q, float* __restrict__ kv, int M, int K) {
  constexpr int BM = 64, BN = 64, BK = 16, PAD = 4;
  __shared__ float As[BK][BM + PAD];
  __shared__ float Bs[BK][BN + PAD];
  const int tid = threadIdx.x;
  const int bm = blockIdx.y, bn = blockIdx.x;
  const int lr = tid >> 2;
  const int lc = (tid & 3) * 4;
  const int tm = tid >> 4;
  const int tn = tid & 15;
  const float* Ab = A + (size_t)bm * BM * K;
  const float* Wb = W + (size_t)bn * BN * K;
  float acc[4][4] = {};
  for (int k0 = 0; k0 < K; k0 += BK) {
    float4 av = *(const float4*)(Ab + (size_t)lr * K + k0 + lc);
    float4 wv = *(const float4*)(Wb + (size_t)lr * K + k0 + lc);
    As[lc + 0][lr] = av.x; As[lc + 1][lr] = av.y;
    As[lc + 2][lr] = av.z; As[lc + 3][lr] = av.w;
    Bs[lc + 0][lr] = wv.x; Bs[lc + 1][lr] = wv.y;
    Bs[lc + 2][lr] = wv.z; Bs[lc + 3][lr] = wv.w;
    __syncthreads();
#pragma unroll
    for (int kk = 0; kk < BK; ++kk) {
      float4 a  = *(const float4*)&As[kk][tm * 4];
      float4 bq = *(const float4*)&Bs[kk][tn * 4];
      float av4[4] = {a.x, a.y, a.z, a.w};
      float bv4[4] = {bq.x, bq.y, bq.z, bq.w};
#pragma unroll
      for (int i = 0; i < 4; ++i)
#pragma unroll
        for (int j = 0; j < 4; ++j) acc[i][j] += av4[i] * bv4[j];
    }
    __syncthreads();
  }
  // route output: bn<12 -> q (ldc=768), else kv (ldc=1536, col-768)
  float* Cb;
  int ldc;
  if (bn < 12) {
    Cb = q + (size_t)bm * BM * kD + (size_t)bn * BN;
    ldc = kD;
  } else {
    Cb = kv + (size_t)bm * BM * (2 * kD) + (size_t)(bn - 12) * BN;
    ldc = 2 * kD;
  }
#pragma unroll
  for (int i = 0; i < 4; ++i) {
    float4 o = make_float4(acc[i][0], acc[i][1], acc[i][2], acc[i][3]);
    *(float4*)(Cb + (size_t)(tm * 4 + i) * ldc + tn * 4) = o;
  }
}

// ---------------- K6: C[M,N] = A[M,K] @ W[N,K]^T ----------------
__global__ __launch_bounds__(256) void sgemm_bt(
    const float* __restrict__ A, const float* __restrict__ W,
    float* __restrict__ C, int M, int N, int K) {
  constexpr int BM = 64, BN = 64, BK = 16, PAD = 4;
  __shared__ float As[BK][BM + PAD];
  __shared__ float Bs[BK][BN + PAD];
  const int tid = threadIdx.x;
  const int bm = blockIdx.y, bn = blockIdx.x;
  const int lr = tid >> 2;
  const int lc = (tid & 3) * 4;
  const int tm = tid >> 4;
  const int tn = tid & 15;
  const float* Ab = A + (size_t)bm * BM * K;
  const float* Wb = W + (size_t)bn * BN * K;
  float acc[4][4] = {};
  for (int k0 = 0; k0 < K; k0 += BK) {
    float4 av = *(const float4*)(Ab + (size_t)lr * K + k0 + lc);
    float4 wv = *(const float4*)(Wb + (size_t)lr * K + k0 + lc);
    As[lc + 0][lr] = av.x; As[lc + 1][lr] = av.y;
    As[lc + 2][lr] = av.z; As[lc + 3][lr] = av.w;
    Bs[lc + 0][lr] = wv.x; Bs[lc + 1][lr] = wv.y;
    Bs[lc + 2][lr] = wv.z; Bs[lc + 3][lr] = wv.w;
    __syncthreads();
#pragma unroll
    for (int kk = 0; kk < BK; ++kk) {
      float4 a  = *(const float4*)&As[kk][tm * 4];
      float4 bq = *(const float4*)&Bs[kk][tn * 4];
      float av4[4] = {a.x, a.y, a.z, a.w};
      float bv4[4] = {bq.x, bq.y, bq.z, bq.w};
#pragma unroll
      for (int i = 0; i < 4; ++i)
#pragma unroll
        for (int j = 0; j < 4; ++j) acc[i][j] += av4[i] * bv4[j];
    }
    __syncthreads();
  }
  float* Cb = C + (size_t)bm * BM * N + (size_t)bn * BN;
#pragma unroll
  for (int i = 0; i < 4; ++i) {
    float4 o = make_float4(acc[i][0], acc[i][1], acc[i][2], acc[i][3]);
    *(float4*)(Cb + (size_t)(tm * 4 + i) * N + tn * 4) = o;
  }
}

// ---------------- K2: depthwise causal conv(k=3) on k,v + product, transpose ----------------
// in: kv [B][L][2D]; out: u [B][D][L],  u = (conv(k)+kb) * (conv(v)+vb)
__global__ __launch_bounds__(256) void dwconv_mul(
    const float* __restrict__ kv,
    const float* __restrict__ sck_w, const float* __restrict__ sck_b,
    const float* __restrict__ scv_w, const float* __restrict__ scv_b,
    float* __restrict__ u) {
  __shared__ float ks[34][33];
  __shared__ float vs[34][33];
  const int b  = blockIdx.z;
  const int d0 = blockIdx.y * 32;
  const int t0 = blockIdx.x * 32;
  const int tx = threadIdx.x;  // 0..31
  const int ty = threadIdx.y;  // 0..7
  const float* base = kv + (size_t)b * kL * (2 * kD);
  for (int r = ty; r < 34; r += 8) {
    int t = t0 - 2 + r;
    float kk = 0.f, vv = 0.f;
    if (t >= 0) {
      kk = base[(size_t)t * (2 * kD) + d0 + tx];
      vv = base[(size_t)t * (2 * kD) + kD + d0 + tx];
    }
    ks[r][tx] = kk;
    vs[r][tx] = vv;
  }
  __syncthreads();
#pragma unroll
  for (int i = 0; i < 4; ++i) {
    int dd = ty + 8 * i;
    int d = d0 + dd;
    float kw0 = sck_w[d * 3 + 0], kw1 = sck_w[d * 3 + 1], kw2 = sck_w[d * 3 + 2];
    float vw0 = scv_w[d * 3 + 0], vw1 = scv_w[d * 3 + 1], vw2 = scv_w[d * 3 + 2];
    float kc = kw0 * ks[tx][dd] + kw1 * ks[tx + 1][dd] + kw2 * ks[tx + 2][dd] + sck_b[d];
    float vc = vw0 * vs[tx][dd] + vw1 * vs[tx + 1][dd] + vw2 * vs[tx + 2][dd] + scv_b[d];
    u[((size_t)b * kD + d) * kL + t0 + tx] = kc * vc;
  }
}

// ---------------- K3: hyena filter  hfd[d][t] = mlp(pos_enc(t))[d] * exp(-|a_d| t) ----------------
__global__ __launch_bounds__(256) void hyena_filter(
    const float* __restrict__ w1, const float* __restrict__ b1,
    const float* __restrict__ w2, const float* __restrict__ b2,
    const float* __restrict__ w3, const float* __restrict__ b3,
    const float* __restrict__ log_decay, float* __restrict__ hfd) {
  __shared__ float w1s[64 * 65];
  __shared__ float w2s[64 * 65];
  __shared__ float h2s[32][64];
  __shared__ float pe[64];
  __shared__ float h1v[64];
  const int tid = threadIdx.x;
  for (int i = tid; i < 64 * 64; i += 256) {
    w1s[(i >> 6) * 65 + (i & 63)] = w1[i];
    w2s[(i >> 6) * 65 + (i & 63)] = w2[i];
  }
  __syncthreads();
  const int tbase = blockIdx.x * 32;
  const float TWO_PI = 6.28318530717958647692f;
  for (int tt = 0; tt < 32; ++tt) {
    int t = tbase + tt;
    float tn = (float)t / 8191.0f;
    if (tid < 64) {
      float f = TWO_PI * (float)((tid & 31) + 1);
      pe[tid] = (tid < 32) ? sinf(tn * f) : cosf(tn * f);
    }
    __syncthreads();
    if (tid < 64) {
      float s = b1[tid];
      for (int j = 0; j < 64; ++j) s += pe[j] * w1s[tid * 65 + j];
      h1v[tid] = s / (1.0f + expf(-s));
    }
    __syncthreads();
    if (tid < 64) {
      float s = b2[tid];
      for (int j = 0; j < 64; ++j) s += h1v[j] * w2s[tid * 65 + j];
      h2s[tt][tid] = s / (1.0f + expf(-s));
    }
    __syncthreads();
  }
  // layer 3 (768x64) + decay; write transposed [D][L]
  for (int d = tid; d < kD; d += 256) {
    float a = fabsf(log_decay[d]);
    float bb = b3[d];
    float acc[32];
#pragma unroll
    for (int tt = 0; tt < 32; ++tt) acc[tt] = bb;
    for (int j = 0; j < 64; ++j) {
      float w = w3[d * 64 + j];
#pragma unroll
      for (int tt = 0; tt < 32; ++tt) acc[tt] += h2s[tt][j] * w;
    }
    for (int tt = 0; tt < 32; ++tt) {
      int t = tbase + tt;
      hfd[(size_t)d * kL + t] = acc[tt] * expf(-a * (float)t);
    }
  }
}

// ---------------- K4: causal long conv  y[b,d,t] = sum_s hfd[d,s] u[b,d,t-s] ----------------
constexpr int CT = 1024;  // t-tile per block
constexpr int CS = 256;   // s-chunk
__global__ __launch_bounds__(256) void long_conv(
    const float* __restrict__ u, const float* __restrict__ hfd,
    const float* __restrict__ log_decay, float* __restrict__ y) {
  const int b  = blockIdx.z;
  const int d  = blockIdx.y;
  const int t0 = blockIdx.x * CT;
  const int tid = threadIdx.x;
  __shared__ float hs[CS];
  __shared__ float us[CT + CS];
  const float a = fabsf(log_decay[d]);
  const float cutoff = 20.0f;
  const int Td = (a * (float)kL <= cutoff) ? kL : ((int)(cutoff / a) + 1);
  const int smax = min(Td, t0 + CT);
  const float* ub = u + ((size_t)b * kD + d) * kL;
  const float* hb = hfd + (size_t)d * kL;
  float acc[4] = {0.f, 0.f, 0.f, 0.f};
  for (int s0 = 0; s0 < smax; s0 += CS) {
    {
      int s = s0 + tid;
      hs[tid] = (s < kL) ? hb[s] : 0.f;
    }
    for (int i = tid; i < CT + CS; i += 256) {
      int t = t0 - s0 - (CS - 1) + i;
      us[i] = (t >= 0 && t < kL) ? ub[t] : 0.f;
    }
    __syncthreads();
#pragma unroll 8
    for (int ss = 0; ss < CS; ++ss) {
      float hv = hs[ss];
#pragma unroll
      for (int q = 0; q < 4; ++q)
        acc[q] += hv * us[tid + q * 256 + (CS - 1) - ss];
    }
    __syncthreads();
  }
#pragma unroll
  for (int q = 0; q < 4; ++q)
    y[((size_t)b * kD + d) * kL + t0 + tid + q * 256] = acc[q];
}

// ---------------- K5: gate + transpose  g[b,t,d] = silu(q[b,t,d]) * y[b,d,t] ----------------
__global__ __launch_bounds__(256) void gate_transpose(
    const float* __restrict__ q, const float* __restrict__ y,
    float* __restrict__ g) {
  __shared__ float ys[32][33];
  const int b  = blockIdx.z;
  const int t0 = blockIdx.x * 32;
  const int d0 = blockIdx.y * 32;
  const int tx = threadIdx.x;  // 0..31
  const int ty = threadIdx.y;  // 0..7
#pragma unroll
  for (int i = 0; i < 4; ++i) {
    int dd = ty + 8 * i;
    ys[dd][tx] = y[((size_t)b * kD + d0 + dd) * kL + t0 + tx];
  }
  __syncthreads();
  const float* qb = q + (size_t)b * kL * kD;
#pragma unroll
  for (int i = 0; i < 4; ++i) {
    int t = t0 + ty + 8 * i;
    int d = d0 + tx;
    float qv = qb[(size_t)t * kD + d];
    float sq = qv / (1.0f + expf(-qv));
    g[((size_t)b * kL + t) * kD + d] = sq * ys[tx][ty + 8 * i];
  }
}

}  // namespace

extern "C" void kernel_launch(void* const* d_in, const int* in_sizes, int n_in,
                              void* d_out, int out_size, void* d_ws, size_t ws_size,
                              hipStream_t stream) {
  const float* x          = (const float*)d_in[0];
  const float* in_proj_w  = (const float*)d_in[1];
  const float* sck_w      = (const float*)d_in[2];
  const float* sck_b      = (const float*)d_in[3];
  const float* scv_w      = (const float*)d_in[4];
  const float* scv_b      = (const float*)d_in[5];
  const float* mlp_w1     = (const float*)d_in[6];
  const float* mlp_b1     = (const float*)d_in[7];
  const float* mlp_w2     = (const float*)d_in[8];
  const float* mlp_b2     = (const float*)d_in[9];
  const float* mlp_w3     = (const float*)d_in[10];
  const float* mlp_b3     = (const float*)d_in[11];
  const float* log_decay  = (const float*)d_in[12];
  const float* out_proj_w = (const float*)d_in[13];
  float* out = (float*)d_out;

  // workspace layout (peak 50,331,648 floats = 201.3 MB)
  float* q   = (float*)d_ws;                      // [B][L][D]    12,582,912
  float* kv  = q + (size_t)kB * kL * kD;          // [B][L][2D]   25,165,824
  float* u   = kv + (size_t)kB * kL * 2 * kD;     // [B][D][L]    12,582,912
  // after K2 consumes kv, reuse its region:
  float* hfd = kv;                                // [D][L]        6,291,456
  float* y   = kv + (size_t)kD * kL;              // [B][D][L]    12,582,912 (fits in kv region)
  float* g   = u;                                 // reuse u: [B][L][D]

  // K1: {q, kv} = x @ in_proj_w^T
  sgemm_qkv<<<dim3(kTD / 64, (kB * kL) / 64), 256, 0, stream>>>(
      x, in_proj_w, q, kv, kB * kL, kD);

  // K2: u[b,d,t] = conv_k * conv_v (transposed layout)
  dwconv_mul<<<dim3(kL / 32, kD / 32, kB), dim3(32, 8), 0, stream>>>(
      kv, sck_w, sck_b, scv_w, scv_b, u);

  // K3: filter hfd[d][t]  (overwrites kv region — safe, kv fully consumed by K2)
  hyena_filter<<<dim3(kL / 32), 256, 0, stream>>>(
      mlp_w1, mlp_b1, mlp_w2, mlp_b2, mlp_w3, mlp_b3, log_decay, hfd);

  // K4: y[b,d,t] = causal conv(u, hfd), per-channel truncated
  long_conv<<<dim3(kL / CT, kD, kB), 256, 0, stream>>>(u, hfd, log_decay, y);

  // K5: g[b,t,d] = silu(q) * y
  gate_transpose<<<dim3(kL / 32, kD / 32, kB), dim3(32, 8), 0, stream>>>(q, y, g);

  // K6: out = g @ out_proj_w^T
  sgemm_bt<<<dim3(kD / 64, (kB * kL) / 64), 256, 0, stream>>>(
      g, out_proj_w, out, kB * kL, kD, kD);
}

// Round 3
// 543.987 us; speedup vs baseline: 2.9652x; 2.9652x over previous
//
#include <hip/hip_runtime.h>
#include <math.h>

namespace {

constexpr int kB  = 2;
constexpr int kL  = 8192;
constexpr int kD  = 768;

typedef _Float16 f16;
typedef __attribute__((ext_vector_type(8))) _Float16 f16x8;
typedef __attribute__((ext_vector_type(4))) float f32x4;

__device__ __forceinline__ void gload_lds16(const f16* g, f16* l) {
  __builtin_amdgcn_global_load_lds(
      (__attribute__((address_space(1))) void*)(g),
      (__attribute__((address_space(3))) void*)(l), 16, 0, 0);
}

// ---------------- K0: fp32 -> fp16 conversion ----------------
__global__ __launch_bounds__(256) void cvt_f32_f16(
    const float* __restrict__ s, f16* __restrict__ d, int n) {
  int t = blockIdx.x * 256 + threadIdx.x;
  int i = t * 8;
  if (i >= n) return;
  float4 a = *(const float4*)(s + i);
  float4 b = *(const float4*)(s + i + 4);
  f16x8 v;
  v[0] = (f16)a.x; v[1] = (f16)a.y; v[2] = (f16)a.z; v[3] = (f16)a.w;
  v[4] = (f16)b.x; v[5] = (f16)b.y; v[6] = (f16)b.z; v[7] = (f16)b.w;
  *(f16x8*)(d + i) = v;
}

// ---------------- K1: qkv projection (fp16 MFMA), split outputs ----------------
// A [M][768] fp16, W [2304][768] fp16 -> q16 [M][768], kv16 [M][1536]
__global__ __launch_bounds__(256) void hgemm_qkv(
    const f16* __restrict__ A, const f16* __restrict__ W,
    f16* __restrict__ q16, f16* __restrict__ kv16, int M) {
  constexpr int K = 768;
  __shared__ f16 As[128 * 32];
  __shared__ f16 Bs[128 * 32];
  const int tid = threadIdx.x;
  const int bm = blockIdx.y, bn = blockIdx.x;
  const int lane = tid & 63;
  const int wv = tid >> 6;
  const int wr = wv >> 1, wc = wv & 1;
  const int fr = lane & 15, fq = lane >> 4;
  const int srow = tid >> 2;
  const int scol = (tid & 3) * 8;
  const f16* Ab = A + (size_t)bm * 128 * K;
  const f16* Wb = W + (size_t)bn * 128 * K;
  f32x4 acc[4][4];
#pragma unroll
  for (int m = 0; m < 4; ++m)
#pragma unroll
    for (int n = 0; n < 4; ++n)
#pragma unroll
      for (int j = 0; j < 4; ++j) acc[m][n][j] = 0.f;

  for (int k0 = 0; k0 < K; k0 += 32) {
#pragma unroll
    for (int i = 0; i < 2; ++i) {
      gload_lds16(Ab + (size_t)(i * 64 + srow) * K + k0 + scol, As + i * 2048 + wv * 512);
      gload_lds16(Wb + (size_t)(i * 64 + srow) * K + k0 + scol, Bs + i * 2048 + wv * 512);
    }
    __syncthreads();
    f16x8 af[4], bf[4];
#pragma unroll
    for (int m = 0; m < 4; ++m)
      af[m] = *(const f16x8*)&As[(wr * 64 + m * 16 + fr) * 32 + fq * 8];
#pragma unroll
    for (int n = 0; n < 4; ++n)
      bf[n] = *(const f16x8*)&Bs[(wc * 64 + n * 16 + fr) * 32 + fq * 8];
#pragma unroll
    for (int m = 0; m < 4; ++m)
#pragma unroll
      for (int n = 0; n < 4; ++n)
        acc[m][n] = __builtin_amdgcn_mfma_f32_16x16x32_f16(af[m], bf[n], acc[m][n], 0, 0, 0);
    __syncthreads();
  }
#pragma unroll
  for (int m = 0; m < 4; ++m) {
    int grow = bm * 128 + wr * 64 + m * 16 + fq * 4;
#pragma unroll
    for (int n = 0; n < 4; ++n) {
      int gcol = bn * 128 + wc * 64 + n * 16 + fr;
      f16* dst;
      int ldc, col;
      if (gcol < 768) { dst = q16; ldc = 768; col = gcol; }
      else            { dst = kv16; ldc = 1536; col = gcol - 768; }
#pragma unroll
      for (int j = 0; j < 4; ++j)
        dst[(size_t)(grow + j) * ldc + col] = (f16)acc[m][n][j];
    }
  }
}

// ---------------- K6: out = g16 @ w16out^T (fp16 MFMA, fp32 out) ----------------
__global__ __launch_bounds__(256) void hgemm_f32out(
    const f16* __restrict__ A, const f16* __restrict__ W,
    float* __restrict__ C, int M, int N) {
  constexpr int K = 768;
  __shared__ f16 As[128 * 32];
  __shared__ f16 Bs[128 * 32];
  const int tid = threadIdx.x;
  const int bm = blockIdx.y, bn = blockIdx.x;
  const int lane = tid & 63;
  const int wv = tid >> 6;
  const int wr = wv >> 1, wc = wv & 1;
  const int fr = lane & 15, fq = lane >> 4;
  const int srow = tid >> 2;
  const int scol = (tid & 3) * 8;
  const f16* Ab = A + (size_t)bm * 128 * K;
  const f16* Wb = W + (size_t)bn * 128 * K;
  f32x4 acc[4][4];
#pragma unroll
  for (int m = 0; m < 4; ++m)
#pragma unroll
    for (int n = 0; n < 4; ++n)
#pragma unroll
      for (int j = 0; j < 4; ++j) acc[m][n][j] = 0.f;

  for (int k0 = 0; k0 < K; k0 += 32) {
#pragma unroll
    for (int i = 0; i < 2; ++i) {
      gload_lds16(Ab + (size_t)(i * 64 + srow) * K + k0 + scol, As + i * 2048 + wv * 512);
      gload_lds16(Wb + (size_t)(i * 64 + srow) * K + k0 + scol, Bs + i * 2048 + wv * 512);
    }
    __syncthreads();
    f16x8 af[4], bf[4];
#pragma unroll
    for (int m = 0; m < 4; ++m)
      af[m] = *(const f16x8*)&As[(wr * 64 + m * 16 + fr) * 32 + fq * 8];
#pragma unroll
    for (int n = 0; n < 4; ++n)
      bf[n] = *(const f16x8*)&Bs[(wc * 64 + n * 16 + fr) * 32 + fq * 8];
#pragma unroll
    for (int m = 0; m < 4; ++m)
#pragma unroll
      for (int n = 0; n < 4; ++n)
        acc[m][n] = __builtin_amdgcn_mfma_f32_16x16x32_f16(af[m], bf[n], acc[m][n], 0, 0, 0);
    __syncthreads();
  }
#pragma unroll
  for (int m = 0; m < 4; ++m) {
    int grow = bm * 128 + wr * 64 + m * 16 + fq * 4;
#pragma unroll
    for (int n = 0; n < 4; ++n) {
      int gcol = bn * 128 + wc * 64 + n * 16 + fr;
#pragma unroll
      for (int j = 0; j < 4; ++j)
        C[(size_t)(grow + j) * N + gcol] = acc[m][n][j];
    }
  }
}

// ---------------- K2: depthwise causal conv(k=3) on k,v + product, transpose ----------------
// in: kv16 [B][L][2D]; out: u16 [B][D][L]
__global__ __launch_bounds__(256) void dwconv_mul(
    const f16* __restrict__ kv,
    const float* __restrict__ sck_w, const float* __restrict__ sck_b,
    const float* __restrict__ scv_w, const float* __restrict__ scv_b,
    f16* __restrict__ u) {
  __shared__ float ks[34][33];
  __shared__ float vs[34][33];
  const int b  = blockIdx.z;
  const int d0 = blockIdx.y * 32;
  const int t0 = blockIdx.x * 32;
  const int tx = threadIdx.x;
  const int ty = threadIdx.y;
  const f16* base = kv + (size_t)b * kL * (2 * kD);
  for (int r = ty; r < 34; r += 8) {
    int t = t0 - 2 + r;
    float kk = 0.f, vv = 0.f;
    if (t >= 0) {
      kk = (float)base[(size_t)t * (2 * kD) + d0 + tx];
      vv = (float)base[(size_t)t * (2 * kD) + kD + d0 + tx];
    }
    ks[r][tx] = kk;
    vs[r][tx] = vv;
  }
  __syncthreads();
#pragma unroll
  for (int i = 0; i < 4; ++i) {
    int dd = ty + 8 * i;
    int d = d0 + dd;
    float kw0 = sck_w[d * 3 + 0], kw1 = sck_w[d * 3 + 1], kw2 = sck_w[d * 3 + 2];
    float vw0 = scv_w[d * 3 + 0], vw1 = scv_w[d * 3 + 1], vw2 = scv_w[d * 3 + 2];
    float kc = kw0 * ks[tx][dd] + kw1 * ks[tx + 1][dd] + kw2 * ks[tx + 2][dd] + sck_b[d];
    float vc = vw0 * vs[tx][dd] + vw1 * vs[tx + 1][dd] + vw2 * vs[tx + 2][dd] + scv_b[d];
    u[((size_t)b * kD + d) * kL + t0 + tx] = (f16)(kc * vc);
  }
}

// ---------------- K3: hyena filter  hfd[d][t] (fp32) ----------------
__global__ __launch_bounds__(256) void hyena_filter(
    const float* __restrict__ w1, const float* __restrict__ b1,
    const float* __restrict__ w2, const float* __restrict__ b2,
    const float* __restrict__ w3, const float* __restrict__ b3,
    const float* __restrict__ log_decay, float* __restrict__ hfd) {
  __shared__ float w1s[64 * 65];
  __shared__ float w2s[64 * 65];
  __shared__ float h2s[32][64];
  __shared__ float pe[64];
  __shared__ float h1v[64];
  const int tid = threadIdx.x;
  for (int i = tid; i < 64 * 64; i += 256) {
    w1s[(i >> 6) * 65 + (i & 63)] = w1[i];
    w2s[(i >> 6) * 65 + (i & 63)] = w2[i];
  }
  __syncthreads();
  const int tbase = blockIdx.x * 32;
  const float TWO_PI = 6.28318530717958647692f;
  for (int tt = 0; tt < 32; ++tt) {
    int t = tbase + tt;
    float tn = (float)t / 8191.0f;
    if (tid < 64) {
      float f = TWO_PI * (float)((tid & 31) + 1);
      pe[tid] = (tid < 32) ? sinf(tn * f) : cosf(tn * f);
    }
    __syncthreads();
    if (tid < 64) {
      float s = b1[tid];
      for (int j = 0; j < 64; ++j) s += pe[j] * w1s[tid * 65 + j];
      h1v[tid] = s / (1.0f + expf(-s));
    }
    __syncthreads();
    if (tid < 64) {
      float s = b2[tid];
      for (int j = 0; j < 64; ++j) s += h1v[j] * w2s[tid * 65 + j];
      h2s[tt][tid] = s / (1.0f + expf(-s));
    }
    __syncthreads();
  }
  for (int d = tid; d < kD; d += 256) {
    float a = fabsf(log_decay[d]);
    float bb = b3[d];
    float acc[32];
#pragma unroll
    for (int tt = 0; tt < 32; ++tt) acc[tt] = bb;
    for (int j = 0; j < 64; ++j) {
      float w = w3[d * 64 + j];
#pragma unroll
      for (int tt = 0; tt < 32; ++tt) acc[tt] += h2s[tt][j] * w;
    }
    for (int tt = 0; tt < 32; ++tt) {
      int t = tbase + tt;
      hfd[(size_t)d * kL + t] = acc[tt] * expf(-a * (float)t);
    }
  }
}

// ---------------- K4: causal long conv, per-channel truncated ----------------
constexpr int CT = 1024;
constexpr int CS = 256;
__global__ __launch_bounds__(256) void long_conv(
    const f16* __restrict__ u, const float* __restrict__ hfd,
    const float* __restrict__ log_decay, float* __restrict__ y) {
  const int b  = blockIdx.z;
  const int d  = blockIdx.y;
  const int t0 = blockIdx.x * CT;
  const int tid = threadIdx.x;
  __shared__ float hs[CS];
  __shared__ float us[CT + CS];
  const float a = fabsf(log_decay[d]);
  const float cutoff = 20.0f;
  const int Td = (a * (float)kL <= cutoff) ? kL : ((int)(cutoff / a) + 1);
  const int smax = min(Td, t0 + CT);
  const f16* ub = u + ((size_t)b * kD + d) * kL;
  const float* hb = hfd + (size_t)d * kL;
  float acc[4] = {0.f, 0.f, 0.f, 0.f};
  for (int s0 = 0; s0 < smax; s0 += CS) {
    {
      int s = s0 + tid;
      hs[tid] = (s < kL) ? hb[s] : 0.f;
    }
    for (int i = tid; i < CT + CS; i += 256) {
      int t = t0 - s0 - (CS - 1) + i;
      us[i] = (t >= 0 && t < kL) ? (float)ub[t] : 0.f;
    }
    __syncthreads();
    const int send = min(CS, smax - s0);
    for (int ss = 0; ss < send; ++ss) {
      float hv = hs[ss];
      int bi = tid + (CS - 1) - ss;
      acc[0] += hv * us[bi];
      acc[1] += hv * us[bi + 256];
      acc[2] += hv * us[bi + 512];
      acc[3] += hv * us[bi + 768];
    }
    __syncthreads();
  }
#pragma unroll
  for (int q = 0; q < 4; ++q)
    y[((size_t)b * kD + d) * kL + t0 + tid + q * 256] = acc[q];
}

// ---------------- K5: gate + transpose  g16[b,t,d] = silu(q16[b,t,d]) * y[b,d,t] ----------------
__global__ __launch_bounds__(256) void gate_transpose(
    const f16* __restrict__ q, const float* __restrict__ y,
    f16* __restrict__ g) {
  __shared__ float ys[32][33];
  const int b  = blockIdx.z;
  const int t0 = blockIdx.x * 32;
  const int d0 = blockIdx.y * 32;
  const int tx = threadIdx.x;
  const int ty = threadIdx.y;
#pragma unroll
  for (int i = 0; i < 4; ++i) {
    int dd = ty + 8 * i;
    ys[dd][tx] = y[((size_t)b * kD + d0 + dd) * kL + t0 + tx];
  }
  __syncthreads();
  const f16* qb = q + (size_t)b * kL * kD;
#pragma unroll
  for (int i = 0; i < 4; ++i) {
    int t = t0 + ty + 8 * i;
    int d = d0 + tx;
    float qv = (float)qb[(size_t)t * kD + d];
    float sq = qv / (1.0f + expf(-qv));
    g[((size_t)b * kL + t) * kD + d] = (f16)(sq * ys[tx][ty + 8 * i]);
  }
}

}  // namespace

extern "C" void kernel_launch(void* const* d_in, const int* in_sizes, int n_in,
                              void* d_out, int out_size, void* d_ws, size_t ws_size,
                              hipStream_t stream) {
  const float* x          = (const float*)d_in[0];
  const float* in_proj_w  = (const float*)d_in[1];
  const float* sck_w      = (const float*)d_in[2];
  const float* sck_b      = (const float*)d_in[3];
  const float* scv_w      = (const float*)d_in[4];
  const float* scv_b      = (const float*)d_in[5];
  const float* mlp_w1     = (const float*)d_in[6];
  const float* mlp_b1     = (const float*)d_in[7];
  const float* mlp_w2     = (const float*)d_in[8];
  const float* mlp_b2     = (const float*)d_in[9];
  const float* mlp_w3     = (const float*)d_in[10];
  const float* mlp_b3     = (const float*)d_in[11];
  const float* log_decay  = (const float*)d_in[12];
  const float* out_proj_w = (const float*)d_in[13];
  float* out = (float*)d_out;

  // workspace layout (bytes), total ~155.7 MB
  char* base = (char*)d_ws;
  const size_t S1 = 25165824;   // q16  [B][L][D] fp16
  const size_t S2 = 50331648;   // kv16 [B][L][2D] fp16  -> later y [B][D][L] fp32
  const size_t S3 = 25165824;   // u16  [B][D][L] fp16
  const size_t S4 = 25165824;   // x16  [B][L][D] fp16   -> later g16 [B][L][D] fp16
  const size_t S5 = 25165824;   // hfd  [D][L] fp32
  f16*   q16   = (f16*)base;
  f16*   kv16  = (f16*)(base + S1);
  float* y     = (float*)(base + S1);
  f16*   u16   = (f16*)(base + S1 + S2);
  f16*   x16   = (f16*)(base + S1 + S2 + S3);
  f16*   g16   = x16;
  float* hfd   = (float*)(base + S1 + S2 + S3 + S4);
  f16*   w16in = (f16*)(base + S1 + S2 + S3 + S4 + S5);
  f16*   w16out= w16in + (size_t)3 * kD * kD;

  // K0: fp32 -> fp16 conversions
  {
    int n1 = kB * kL * kD;        // 12,582,912
    int n2 = 3 * kD * kD;         // 1,769,472
    int n3 = kD * kD;             // 589,824
    cvt_f32_f16<<<(n1 / 8 + 255) / 256, 256, 0, stream>>>(x, x16, n1);
    cvt_f32_f16<<<(n2 / 8 + 255) / 256, 256, 0, stream>>>(in_proj_w, w16in, n2);
    cvt_f32_f16<<<(n3 / 8 + 255) / 256, 256, 0, stream>>>(out_proj_w, w16out, n3);
  }

  // K1: {q16, kv16} = x16 @ w16in^T  (M=16384, N=2304, K=768)
  hgemm_qkv<<<dim3(18, 128), 256, 0, stream>>>(x16, w16in, q16, kv16, kB * kL);

  // K2: u16[b,d,t] = conv_k * conv_v
  dwconv_mul<<<dim3(kL / 32, kD / 32, kB), dim3(32, 8), 0, stream>>>(
      kv16, sck_w, sck_b, scv_w, scv_b, u16);

  // K3: filter hfd[d][t]
  hyena_filter<<<dim3(kL / 32), 256, 0, stream>>>(
      mlp_w1, mlp_b1, mlp_w2, mlp_b2, mlp_w3, mlp_b3, log_decay, hfd);

  // K4: y[b,d,t] = causal conv(u16, hfd)   (y overwrites kv16 region — kv16 dead)
  long_conv<<<dim3(kL / CT, kD, kB), 256, 0, stream>>>(u16, hfd, log_decay, y);

  // K5: g16[b,t,d] = silu(q16) * y
  gate_transpose<<<dim3(kL / 32, kD / 32, kB), dim3(32, 8), 0, stream>>>(q16, y, g16);

  // K6: out = g16 @ w16out^T  (M=16384, N=768, K=768)
  hgemm_f32out<<<dim3(6, 128), 256, 0, stream>>>(g16, w16out, out, kB * kL, kD);
}

// Round 4
// 516.859 us; speedup vs baseline: 3.1209x; 1.0525x over previous
//
#include <hip/hip_runtime.h>
#include <math.h>

namespace {

constexpr int kB  = 2;
constexpr int kL  = 8192;
constexpr int kD  = 768;

typedef _Float16 f16;
typedef __attribute__((ext_vector_type(8))) _Float16 f16x8;
typedef __attribute__((ext_vector_type(4))) float f32x4;

__device__ __forceinline__ void gload_lds16(const f16* g, f16* l) {
  __builtin_amdgcn_global_load_lds(
      (__attribute__((address_space(1))) void*)(g),
      (__attribute__((address_space(3))) void*)(l), 16, 0, 0);
}

// ---------------- K0: fp32 -> fp16 conversion ----------------
__global__ __launch_bounds__(256) void cvt_f32_f16(
    const float* __restrict__ s, f16* __restrict__ d, int n) {
  int t = blockIdx.x * 256 + threadIdx.x;
  int i = t * 8;
  if (i >= n) return;
  float4 a = *(const float4*)(s + i);
  float4 b = *(const float4*)(s + i + 4);
  f16x8 v;
  v[0] = (f16)a.x; v[1] = (f16)a.y; v[2] = (f16)a.z; v[3] = (f16)a.w;
  v[4] = (f16)b.x; v[5] = (f16)b.y; v[6] = (f16)b.z; v[7] = (f16)b.w;
  *(f16x8*)(d + i) = v;
}

// ---------------- K1: qkv projection (fp16 MFMA), split outputs ----------------
__global__ __launch_bounds__(256) void hgemm_qkv(
    const f16* __restrict__ A, const f16* __restrict__ W,
    f16* __restrict__ q16, f16* __restrict__ kv16, int M) {
  constexpr int K = 768;
  __shared__ f16 As[128 * 32];
  __shared__ f16 Bs[128 * 32];
  const int tid = threadIdx.x;
  const int bm = blockIdx.y, bn = blockIdx.x;
  const int lane = tid & 63;
  const int wv = tid >> 6;
  const int wr = wv >> 1, wc = wv & 1;
  const int fr = lane & 15, fq = lane >> 4;
  const int srow = tid >> 2;
  const int scol = (tid & 3) * 8;
  const f16* Ab = A + (size_t)bm * 128 * K;
  const f16* Wb = W + (size_t)bn * 128 * K;
  f32x4 acc[4][4];
#pragma unroll
  for (int m = 0; m < 4; ++m)
#pragma unroll
    for (int n = 0; n < 4; ++n)
#pragma unroll
      for (int j = 0; j < 4; ++j) acc[m][n][j] = 0.f;

  for (int k0 = 0; k0 < K; k0 += 32) {
#pragma unroll
    for (int i = 0; i < 2; ++i) {
      gload_lds16(Ab + (size_t)(i * 64 + srow) * K + k0 + scol, As + i * 2048 + wv * 512);
      gload_lds16(Wb + (size_t)(i * 64 + srow) * K + k0 + scol, Bs + i * 2048 + wv * 512);
    }
    __syncthreads();
    f16x8 af[4], bf[4];
#pragma unroll
    for (int m = 0; m < 4; ++m)
      af[m] = *(const f16x8*)&As[(wr * 64 + m * 16 + fr) * 32 + fq * 8];
#pragma unroll
    for (int n = 0; n < 4; ++n)
      bf[n] = *(const f16x8*)&Bs[(wc * 64 + n * 16 + fr) * 32 + fq * 8];
#pragma unroll
    for (int m = 0; m < 4; ++m)
#pragma unroll
      for (int n = 0; n < 4; ++n)
        acc[m][n] = __builtin_amdgcn_mfma_f32_16x16x32_f16(af[m], bf[n], acc[m][n], 0, 0, 0);
    __syncthreads();
  }
#pragma unroll
  for (int m = 0; m < 4; ++m) {
    int grow = bm * 128 + wr * 64 + m * 16 + fq * 4;
#pragma unroll
    for (int n = 0; n < 4; ++n) {
      int gcol = bn * 128 + wc * 64 + n * 16 + fr;
      f16* dst;
      int ldc, col;
      if (gcol < 768) { dst = q16; ldc = 768; col = gcol; }
      else            { dst = kv16; ldc = 1536; col = gcol - 768; }
#pragma unroll
      for (int j = 0; j < 4; ++j)
        dst[(size_t)(grow + j) * ldc + col] = (f16)acc[m][n][j];
    }
  }
}

// ---------------- K6: out = g16 @ w16out^T (fp16 MFMA, fp32 out) ----------------
__global__ __launch_bounds__(256) void hgemm_f32out(
    const f16* __restrict__ A, const f16* __restrict__ W,
    float* __restrict__ C, int M, int N) {
  constexpr int K = 768;
  __shared__ f16 As[128 * 32];
  __shared__ f16 Bs[128 * 32];
  const int tid = threadIdx.x;
  const int bm = blockIdx.y, bn = blockIdx.x;
  const int lane = tid & 63;
  const int wv = tid >> 6;
  const int wr = wv >> 1, wc = wv & 1;
  const int fr = lane & 15, fq = lane >> 4;
  const int srow = tid >> 2;
  const int scol = (tid & 3) * 8;
  const f16* Ab = A + (size_t)bm * 128 * K;
  const f16* Wb = W + (size_t)bn * 128 * K;
  f32x4 acc[4][4];
#pragma unroll
  for (int m = 0; m < 4; ++m)
#pragma unroll
    for (int n = 0; n < 4; ++n)
#pragma unroll
      for (int j = 0; j < 4; ++j) acc[m][n][j] = 0.f;

  for (int k0 = 0; k0 < K; k0 += 32) {
#pragma unroll
    for (int i = 0; i < 2; ++i) {
      gload_lds16(Ab + (size_t)(i * 64 + srow) * K + k0 + scol, As + i * 2048 + wv * 512);
      gload_lds16(Wb + (size_t)(i * 64 + srow) * K + k0 + scol, Bs + i * 2048 + wv * 512);
    }
    __syncthreads();
    f16x8 af[4], bf[4];
#pragma unroll
    for (int m = 0; m < 4; ++m)
      af[m] = *(const f16x8*)&As[(wr * 64 + m * 16 + fr) * 32 + fq * 8];
#pragma unroll
    for (int n = 0; n < 4; ++n)
      bf[n] = *(const f16x8*)&Bs[(wc * 64 + n * 16 + fr) * 32 + fq * 8];
#pragma unroll
    for (int m = 0; m < 4; ++m)
#pragma unroll
      for (int n = 0; n < 4; ++n)
        acc[m][n] = __builtin_amdgcn_mfma_f32_16x16x32_f16(af[m], bf[n], acc[m][n], 0, 0, 0);
    __syncthreads();
  }
#pragma unroll
  for (int m = 0; m < 4; ++m) {
    int grow = bm * 128 + wr * 64 + m * 16 + fq * 4;
#pragma unroll
    for (int n = 0; n < 4; ++n) {
      int gcol = bn * 128 + wc * 64 + n * 16 + fr;
#pragma unroll
      for (int j = 0; j < 4; ++j)
        C[(size_t)(grow + j) * N + gcol] = acc[m][n][j];
    }
  }
}

// ---------------- K2: depthwise causal conv(k=3) on k,v + product, transpose ----------------
__global__ __launch_bounds__(256) void dwconv_mul(
    const f16* __restrict__ kv,
    const float* __restrict__ sck_w, const float* __restrict__ sck_b,
    const float* __restrict__ scv_w, const float* __restrict__ scv_b,
    f16* __restrict__ u) {
  __shared__ float ks[34][33];
  __shared__ float vs[34][33];
  const int b  = blockIdx.z;
  const int d0 = blockIdx.y * 32;
  const int t0 = blockIdx.x * 32;
  const int tx = threadIdx.x;
  const int ty = threadIdx.y;
  const f16* base = kv + (size_t)b * kL * (2 * kD);
  for (int r = ty; r < 34; r += 8) {
    int t = t0 - 2 + r;
    float kk = 0.f, vv = 0.f;
    if (t >= 0) {
      kk = (float)base[(size_t)t * (2 * kD) + d0 + tx];
      vv = (float)base[(size_t)t * (2 * kD) + kD + d0 + tx];
    }
    ks[r][tx] = kk;
    vs[r][tx] = vv;
  }
  __syncthreads();
#pragma unroll
  for (int i = 0; i < 4; ++i) {
    int dd = ty + 8 * i;
    int d = d0 + dd;
    float kw0 = sck_w[d * 3 + 0], kw1 = sck_w[d * 3 + 1], kw2 = sck_w[d * 3 + 2];
    float vw0 = scv_w[d * 3 + 0], vw1 = scv_w[d * 3 + 1], vw2 = scv_w[d * 3 + 2];
    float kc = kw0 * ks[tx][dd] + kw1 * ks[tx + 1][dd] + kw2 * ks[tx + 2][dd] + sck_b[d];
    float vc = vw0 * vs[tx][dd] + vw1 * vs[tx + 1][dd] + vw2 * vs[tx + 2][dd] + scv_b[d];
    u[((size_t)b * kD + d) * kL + t0 + tx] = (f16)(kc * vc);
  }
}

// ---------------- K3: hyena filter  hfd[d][t] (fp32) ----------------
__global__ __launch_bounds__(256) void hyena_filter(
    const float* __restrict__ w1, const float* __restrict__ b1,
    const float* __restrict__ w2, const float* __restrict__ b2,
    const float* __restrict__ w3, const float* __restrict__ b3,
    const float* __restrict__ log_decay, float* __restrict__ hfd) {
  __shared__ float w1s[64 * 65];
  __shared__ float w2s[64 * 65];
  __shared__ float h2s[32][64];
  __shared__ float pe[64];
  __shared__ float h1v[64];
  const int tid = threadIdx.x;
  for (int i = tid; i < 64 * 64; i += 256) {
    w1s[(i >> 6) * 65 + (i & 63)] = w1[i];
    w2s[(i >> 6) * 65 + (i & 63)] = w2[i];
  }
  __syncthreads();
  const int tbase = blockIdx.x * 32;
  const float TWO_PI = 6.28318530717958647692f;
  for (int tt = 0; tt < 32; ++tt) {
    int t = tbase + tt;
    float tn = (float)t / 8191.0f;
    if (tid < 64) {
      float f = TWO_PI * (float)((tid & 31) + 1);
      pe[tid] = (tid < 32) ? sinf(tn * f) : cosf(tn * f);
    }
    __syncthreads();
    if (tid < 64) {
      float s = b1[tid];
      for (int j = 0; j < 64; ++j) s += pe[j] * w1s[tid * 65 + j];
      h1v[tid] = s / (1.0f + expf(-s));
    }
    __syncthreads();
    if (tid < 64) {
      float s = b2[tid];
      for (int j = 0; j < 64; ++j) s += h1v[j] * w2s[tid * 65 + j];
      h2s[tt][tid] = s / (1.0f + expf(-s));
    }
    __syncthreads();
  }
  for (int d = tid; d < kD; d += 256) {
    float a = fabsf(log_decay[d]);
    float bb = b3[d];
    float acc[32];
#pragma unroll
    for (int tt = 0; tt < 32; ++tt) acc[tt] = bb;
    for (int j = 0; j < 64; ++j) {
      float w = w3[d * 64 + j];
#pragma unroll
      for (int tt = 0; tt < 32; ++tt) acc[tt] += h2s[tt][j] * w;
    }
    for (int tt = 0; tt < 32; ++tt) {
      int t = tbase + tt;
      hfd[(size_t)d * kL + t] = acc[tt] * expf(-a * (float)t);
    }
  }
}

// ---------------- K4: causal long conv, per-channel truncated ----------------
// 4 outputs/thread, sliding float4 window: per 4 taps = 1 ds_read_b128 (u)
// + 1 broadcast float4 (h) + 16 FMA.
constexpr int CT = 1024;
constexpr int CS = 256;
__global__ __launch_bounds__(256) void long_conv(
    const f16* __restrict__ u, const float* __restrict__ hfd,
    const float* __restrict__ log_decay, float* __restrict__ y) {
  const int b  = blockIdx.z;
  const int d  = blockIdx.y;
  const int t0 = blockIdx.x * CT;
  const int tid = threadIdx.x;
  __shared__ __align__(16) float hs[CS];
  __shared__ __align__(16) float us[CT + CS];  // us[i] = u[t0 - s0 - (CS-1) + i]
  const float a = fabsf(log_decay[d]);
  const int Td = (a * (float)kL <= 20.0f) ? kL : ((int)(20.0f / a) + 1);
  const int smax = min(Td, t0 + CT);
  const f16* ub = u + ((size_t)b * kD + d) * kL;
  const float* hb = hfd + (size_t)d * kL;
  float4 acc = make_float4(0.f, 0.f, 0.f, 0.f);
  for (int s0 = 0; s0 < smax; s0 += CS) {
    hs[tid] = hb[s0 + tid];
#pragma unroll
    for (int i = 0; i < 5; ++i) {
      int idx = tid + i * 256;
      int t = t0 - s0 - (CS - 1) + idx;
      us[idx] = (t >= 0) ? (float)ub[t] : 0.f;
    }
    __syncthreads();
    const int send = min(CS, ((smax - s0) + 3) & ~3);
    // window W[j] = us[4*tid + 252 - ss + j], j=0..6
    float4 hi4 = *(const float4*)&us[4 * tid + 256];
    for (int ss = 0; ss < send; ss += 4) {
      float4 lo4 = *(const float4*)&us[4 * tid + 252 - ss];
      float4 h4  = *(const float4*)&hs[ss];
      acc.x += h4.x * lo4.w; acc.y += h4.x * hi4.x; acc.z += h4.x * hi4.y; acc.w += h4.x * hi4.z;
      acc.x += h4.y * lo4.z; acc.y += h4.y * lo4.w; acc.z += h4.y * hi4.x; acc.w += h4.y * hi4.y;
      acc.x += h4.z * lo4.y; acc.y += h4.z * lo4.z; acc.z += h4.z * lo4.w; acc.w += h4.z * hi4.x;
      acc.x += h4.w * lo4.x; acc.y += h4.w * lo4.y; acc.z += h4.w * lo4.z; acc.w += h4.w * lo4.w;
      hi4 = lo4;
    }
    __syncthreads();
  }
  *(float4*)&y[((size_t)b * kD + d) * kL + t0 + 4 * tid] = acc;
}

// ---------------- K5: gate + transpose  g16[b,t,d] = silu(q16[b,t,d]) * y[b,d,t] ----------------
__global__ __launch_bounds__(256) void gate_transpose(
    const f16* __restrict__ q, const float* __restrict__ y,
    f16* __restrict__ g) {
  __shared__ float ys[32][33];
  const int b  = blockIdx.z;
  const int t0 = blockIdx.x * 32;
  const int d0 = blockIdx.y * 32;
  const int tx = threadIdx.x;
  const int ty = threadIdx.y;
#pragma unroll
  for (int i = 0; i < 4; ++i) {
    int dd = ty + 8 * i;
    ys[dd][tx] = y[((size_t)b * kD + d0 + dd) * kL + t0 + tx];
  }
  __syncthreads();
  const f16* qb = q + (size_t)b * kL * kD;
#pragma unroll
  for (int i = 0; i < 4; ++i) {
    int t = t0 + ty + 8 * i;
    int d = d0 + tx;
    float qv = (float)qb[(size_t)t * kD + d];
    float sq = qv / (1.0f + expf(-qv));
    g[((size_t)b * kL + t) * kD + d] = (f16)(sq * ys[tx][ty + 8 * i]);
  }
}

}  // namespace

extern "C" void kernel_launch(void* const* d_in, const int* in_sizes, int n_in,
                              void* d_out, int out_size, void* d_ws, size_t ws_size,
                              hipStream_t stream) {
  const float* x          = (const float*)d_in[0];
  const float* in_proj_w  = (const float*)d_in[1];
  const float* sck_w      = (const float*)d_in[2];
  const float* sck_b      = (const float*)d_in[3];
  const float* scv_w      = (const float*)d_in[4];
  const float* scv_b      = (const float*)d_in[5];
  const float* mlp_w1     = (const float*)d_in[6];
  const float* mlp_b1     = (const float*)d_in[7];
  const float* mlp_w2     = (const float*)d_in[8];
  const float* mlp_b2     = (const float*)d_in[9];
  const float* mlp_w3     = (const float*)d_in[10];
  const float* mlp_b3     = (const float*)d_in[11];
  const float* log_decay  = (const float*)d_in[12];
  const float* out_proj_w = (const float*)d_in[13];
  float* out = (float*)d_out;

  // workspace layout (bytes), total ~155.7 MB
  char* base = (char*)d_ws;
  const size_t S1 = 25165824;   // q16  [B][L][D] fp16
  const size_t S2 = 50331648;   // kv16 [B][L][2D] fp16  -> later y [B][D][L] fp32
  const size_t S3 = 25165824;   // u16  [B][D][L] fp16
  const size_t S4 = 25165824;   // x16  [B][L][D] fp16   -> later g16
  const size_t S5 = 25165824;   // hfd  [D][L] fp32
  f16*   q16   = (f16*)base;
  f16*   kv16  = (f16*)(base + S1);
  float* y     = (float*)(base + S1);
  f16*   u16   = (f16*)(base + S1 + S2);
  f16*   x16   = (f16*)(base + S1 + S2 + S3);
  f16*   g16   = x16;
  float* hfd   = (float*)(base + S1 + S2 + S3 + S4);
  f16*   w16in = (f16*)(base + S1 + S2 + S3 + S4 + S5);
  f16*   w16out= w16in + (size_t)3 * kD * kD;

  // K0: fp32 -> fp16 conversions
  {
    int n1 = kB * kL * kD;
    int n2 = 3 * kD * kD;
    int n3 = kD * kD;
    cvt_f32_f16<<<(n1 / 8 + 255) / 256, 256, 0, stream>>>(x, x16, n1);
    cvt_f32_f16<<<(n2 / 8 + 255) / 256, 256, 0, stream>>>(in_proj_w, w16in, n2);
    cvt_f32_f16<<<(n3 / 8 + 255) / 256, 256, 0, stream>>>(out_proj_w, w16out, n3);
  }

  // K1: {q16, kv16} = x16 @ w16in^T  (M=16384, N=2304, K=768)
  hgemm_qkv<<<dim3(18, 128), 256, 0, stream>>>(x16, w16in, q16, kv16, kB * kL);

  // K2: u16[b,d,t] = conv_k * conv_v
  dwconv_mul<<<dim3(kL / 32, kD / 32, kB), dim3(32, 8), 0, stream>>>(
      kv16, sck_w, sck_b, scv_w, scv_b, u16);

  // K3: filter hfd[d][t]
  hyena_filter<<<dim3(kL / 32), 256, 0, stream>>>(
      mlp_w1, mlp_b1, mlp_w2, mlp_b2, mlp_w3, mlp_b3, log_decay, hfd);

  // K4: y[b,d,t] = causal conv(u16, hfd)   (y overwrites kv16 region — kv16 dead)
  long_conv<<<dim3(kL / CT, kD, kB), 256, 0, stream>>>(u16, hfd, log_decay, y);

  // K5: g16[b,t,d] = silu(q16) * y
  gate_transpose<<<dim3(kL / 32, kD / 32, kB), dim3(32, 8), 0, stream>>>(q16, y, g16);

  // K6: out = g16 @ w16out^T  (M=16384, N=768, K=768)
  hgemm_f32out<<<dim3(6, 128), 256, 0, stream>>>(g16, w16out, out, kB * kL, kD);
}

// Round 5
// 420.612 us; speedup vs baseline: 3.8350x; 1.2288x over previous
//
#include <hip/hip_runtime.h>
#include <math.h>

namespace {

constexpr int kB  = 2;
constexpr int kL  = 8192;
constexpr int kD  = 768;

typedef _Float16 f16;
typedef __attribute__((ext_vector_type(8))) _Float16 f16x8;
typedef __attribute__((ext_vector_type(4))) float f32x4;

__device__ __forceinline__ void gload_lds16(const f16* g, f16* l) {
  __builtin_amdgcn_global_load_lds(
      (__attribute__((address_space(1))) void*)(g),
      (__attribute__((address_space(3))) void*)(l), 16, 0, 0);
}

// ---------------- K0: fp32 -> fp16 conversion ----------------
__global__ __launch_bounds__(256) void cvt_f32_f16(
    const float* __restrict__ s, f16* __restrict__ d, int n) {
  int t = blockIdx.x * 256 + threadIdx.x;
  int i = t * 8;
  if (i >= n) return;
  float4 a = *(const float4*)(s + i);
  float4 b = *(const float4*)(s + i + 4);
  f16x8 v;
  v[0] = (f16)a.x; v[1] = (f16)a.y; v[2] = (f16)a.z; v[3] = (f16)a.w;
  v[4] = (f16)b.x; v[5] = (f16)b.y; v[6] = (f16)b.z; v[7] = (f16)b.w;
  *(f16x8*)(d + i) = v;
}

// ---------------- K1: qkv projection (fp16 MFMA), split outputs ----------------
__global__ __launch_bounds__(256) void hgemm_qkv(
    const f16* __restrict__ A, const f16* __restrict__ W,
    f16* __restrict__ q16, f16* __restrict__ kv16, int M) {
  constexpr int K = 768;
  __shared__ f16 As[128 * 32];
  __shared__ f16 Bs[128 * 32];
  const int tid = threadIdx.x;
  const int bm = blockIdx.y, bn = blockIdx.x;
  const int lane = tid & 63;
  const int wv = tid >> 6;
  const int wr = wv >> 1, wc = wv & 1;
  const int fr = lane & 15, fq = lane >> 4;
  const int srow = tid >> 2;
  const int scol = (tid & 3) * 8;
  const f16* Ab = A + (size_t)bm * 128 * K;
  const f16* Wb = W + (size_t)bn * 128 * K;
  f32x4 acc[4][4];
#pragma unroll
  for (int m = 0; m < 4; ++m)
#pragma unroll
    for (int n = 0; n < 4; ++n)
#pragma unroll
      for (int j = 0; j < 4; ++j) acc[m][n][j] = 0.f;

  for (int k0 = 0; k0 < K; k0 += 32) {
#pragma unroll
    for (int i = 0; i < 2; ++i) {
      gload_lds16(Ab + (size_t)(i * 64 + srow) * K + k0 + scol, As + i * 2048 + wv * 512);
      gload_lds16(Wb + (size_t)(i * 64 + srow) * K + k0 + scol, Bs + i * 2048 + wv * 512);
    }
    __syncthreads();
    f16x8 af[4], bf[4];
#pragma unroll
    for (int m = 0; m < 4; ++m)
      af[m] = *(const f16x8*)&As[(wr * 64 + m * 16 + fr) * 32 + fq * 8];
#pragma unroll
    for (int n = 0; n < 4; ++n)
      bf[n] = *(const f16x8*)&Bs[(wc * 64 + n * 16 + fr) * 32 + fq * 8];
#pragma unroll
    for (int m = 0; m < 4; ++m)
#pragma unroll
      for (int n = 0; n < 4; ++n)
        acc[m][n] = __builtin_amdgcn_mfma_f32_16x16x32_f16(af[m], bf[n], acc[m][n], 0, 0, 0);
    __syncthreads();
  }
#pragma unroll
  for (int m = 0; m < 4; ++m) {
    int grow = bm * 128 + wr * 64 + m * 16 + fq * 4;
#pragma unroll
    for (int n = 0; n < 4; ++n) {
      int gcol = bn * 128 + wc * 64 + n * 16 + fr;
      f16* dst;
      int ldc, col;
      if (gcol < 768) { dst = q16; ldc = 768; col = gcol; }
      else            { dst = kv16; ldc = 1536; col = gcol - 768; }
#pragma unroll
      for (int j = 0; j < 4; ++j)
        dst[(size_t)(grow + j) * ldc + col] = (f16)acc[m][n][j];
    }
  }
}

// ---------------- K6: out = g16 @ w16out^T (fp16 MFMA, fp32 out) ----------------
__global__ __launch_bounds__(256) void hgemm_f32out(
    const f16* __restrict__ A, const f16* __restrict__ W,
    float* __restrict__ C, int M, int N) {
  constexpr int K = 768;
  __shared__ f16 As[128 * 32];
  __shared__ f16 Bs[128 * 32];
  const int tid = threadIdx.x;
  const int bm = blockIdx.y, bn = blockIdx.x;
  const int lane = tid & 63;
  const int wv = tid >> 6;
  const int wr = wv >> 1, wc = wv & 1;
  const int fr = lane & 15, fq = lane >> 4;
  const int srow = tid >> 2;
  const int scol = (tid & 3) * 8;
  const f16* Ab = A + (size_t)bm * 128 * K;
  const f16* Wb = W + (size_t)bn * 128 * K;
  f32x4 acc[4][4];
#pragma unroll
  for (int m = 0; m < 4; ++m)
#pragma unroll
    for (int n = 0; n < 4; ++n)
#pragma unroll
      for (int j = 0; j < 4; ++j) acc[m][n][j] = 0.f;

  for (int k0 = 0; k0 < K; k0 += 32) {
#pragma unroll
    for (int i = 0; i < 2; ++i) {
      gload_lds16(Ab + (size_t)(i * 64 + srow) * K + k0 + scol, As + i * 2048 + wv * 512);
      gload_lds16(Wb + (size_t)(i * 64 + srow) * K + k0 + scol, Bs + i * 2048 + wv * 512);
    }
    __syncthreads();
    f16x8 af[4], bf[4];
#pragma unroll
    for (int m = 0; m < 4; ++m)
      af[m] = *(const f16x8*)&As[(wr * 64 + m * 16 + fr) * 32 + fq * 8];
#pragma unroll
    for (int n = 0; n < 4; ++n)
      bf[n] = *(const f16x8*)&Bs[(wc * 64 + n * 16 + fr) * 32 + fq * 8];
#pragma unroll
    for (int m = 0; m < 4; ++m)
#pragma unroll
      for (int n = 0; n < 4; ++n)
        acc[m][n] = __builtin_amdgcn_mfma_f32_16x16x32_f16(af[m], bf[n], acc[m][n], 0, 0, 0);
    __syncthreads();
  }
#pragma unroll
  for (int m = 0; m < 4; ++m) {
    int grow = bm * 128 + wr * 64 + m * 16 + fq * 4;
#pragma unroll
    for (int n = 0; n < 4; ++n) {
      int gcol = bn * 128 + wc * 64 + n * 16 + fr;
#pragma unroll
      for (int j = 0; j < 4; ++j)
        C[(size_t)(grow + j) * N + gcol] = acc[m][n][j];
    }
  }
}

// ---------------- K2: depthwise causal conv(k=3) on k,v + product, transpose ----------------
__global__ __launch_bounds__(256) void dwconv_mul(
    const f16* __restrict__ kv,
    const float* __restrict__ sck_w, const float* __restrict__ sck_b,
    const float* __restrict__ scv_w, const float* __restrict__ scv_b,
    f16* __restrict__ u) {
  __shared__ float ks[34][33];
  __shared__ float vs[34][33];
  const int b  = blockIdx.z;
  const int d0 = blockIdx.y * 32;
  const int t0 = blockIdx.x * 32;
  const int tx = threadIdx.x;
  const int ty = threadIdx.y;
  const f16* base = kv + (size_t)b * kL * (2 * kD);
  for (int r = ty; r < 34; r += 8) {
    int t = t0 - 2 + r;
    float kk = 0.f, vv = 0.f;
    if (t >= 0) {
      kk = (float)base[(size_t)t * (2 * kD) + d0 + tx];
      vv = (float)base[(size_t)t * (2 * kD) + kD + d0 + tx];
    }
    ks[r][tx] = kk;
    vs[r][tx] = vv;
  }
  __syncthreads();
#pragma unroll
  for (int i = 0; i < 4; ++i) {
    int dd = ty + 8 * i;
    int d = d0 + dd;
    float kw0 = sck_w[d * 3 + 0], kw1 = sck_w[d * 3 + 1], kw2 = sck_w[d * 3 + 2];
    float vw0 = scv_w[d * 3 + 0], vw1 = scv_w[d * 3 + 1], vw2 = scv_w[d * 3 + 2];
    float kc = kw0 * ks[tx][dd] + kw1 * ks[tx + 1][dd] + kw2 * ks[tx + 2][dd] + sck_b[d];
    float vc = vw0 * vs[tx][dd] + vw1 * vs[tx + 1][dd] + vw2 * vs[tx + 2][dd] + scv_b[d];
    u[((size_t)b * kD + d) * kL + t0 + tx] = (f16)(kc * vc);
  }
}

// ---------------- K3: hyena filter  hfd[d][t] (fp32) ----------------
__global__ __launch_bounds__(256) void hyena_filter(
    const float* __restrict__ w1, const float* __restrict__ b1,
    const float* __restrict__ w2, const float* __restrict__ b2,
    const float* __restrict__ w3, const float* __restrict__ b3,
    const float* __restrict__ log_decay, float* __restrict__ hfd) {
  __shared__ float w1s[64 * 65];
  __shared__ float w2s[64 * 65];
  __shared__ float h2s[32][64];
  __shared__ float pe[64];
  __shared__ float h1v[64];
  const int tid = threadIdx.x;
  for (int i = tid; i < 64 * 64; i += 256) {
    w1s[(i >> 6) * 65 + (i & 63)] = w1[i];
    w2s[(i >> 6) * 65 + (i & 63)] = w2[i];
  }
  __syncthreads();
  const int tbase = blockIdx.x * 32;
  const float TWO_PI = 6.28318530717958647692f;
  for (int tt = 0; tt < 32; ++tt) {
    int t = tbase + tt;
    float tn = (float)t / 8191.0f;
    if (tid < 64) {
      float f = TWO_PI * (float)((tid & 31) + 1);
      pe[tid] = (tid < 32) ? sinf(tn * f) : cosf(tn * f);
    }
    __syncthreads();
    if (tid < 64) {
      float s = b1[tid];
      for (int j = 0; j < 64; ++j) s += pe[j] * w1s[tid * 65 + j];
      h1v[tid] = s / (1.0f + expf(-s));
    }
    __syncthreads();
    if (tid < 64) {
      float s = b2[tid];
      for (int j = 0; j < 64; ++j) s += h1v[j] * w2s[tid * 65 + j];
      h2s[tt][tid] = s / (1.0f + expf(-s));
    }
    __syncthreads();
  }
  for (int d = tid; d < kD; d += 256) {
    float a = fabsf(log_decay[d]);
    float bb = b3[d];
    float acc[32];
#pragma unroll
    for (int tt = 0; tt < 32; ++tt) acc[tt] = bb;
    for (int j = 0; j < 64; ++j) {
      float w = w3[d * 64 + j];
#pragma unroll
      for (int tt = 0; tt < 32; ++tt) acc[tt] += h2s[tt][j] * w;
    }
    for (int tt = 0; tt < 32; ++tt) {
      int t = tbase + tt;
      hfd[(size_t)d * kL + t] = acc[tt] * expf(-a * (float)t);
    }
  }
}

// ---------------- K4: causal long conv, s-parallel, per-channel truncated ----------------
// grid: (kL/CT, kD, kB * NSC); block z handles s-range [sc*SC, (sc+1)*SC).
// Most blocks (sc>0 on short channels) exit immediately -> no straggler tail.
constexpr int CT  = 1024;
constexpr int CS  = 256;
constexpr int SC  = 1024;  // s-range per block
constexpr int NSC = kL / SC;  // 8
__global__ __launch_bounds__(256) void long_conv(
    const f16* __restrict__ u, const float* __restrict__ hfd,
    const float* __restrict__ log_decay, float* __restrict__ y) {
  const int d  = blockIdx.y;
  const int t0 = blockIdx.x * CT;
  const int z  = blockIdx.z;
  const int b  = z >> 3;
  const int sc = z & (NSC - 1);
  const int tid = threadIdx.x;
  const float a = fabsf(log_decay[d]);
  const int Td = (a * (float)kL <= 20.0f) ? kL : ((int)(20.0f / a) + 1);
  const int smax = min(Td, t0 + CT);
  const int s_begin = sc * SC;
  const int s_end = min(s_begin + SC, smax);
  if (s_begin >= s_end) return;

  __shared__ __align__(16) float hs[CS];
  __shared__ __align__(16) float us[CT + CS];
  const f16* ub = u + ((size_t)b * kD + d) * kL;
  const float* hb = hfd + (size_t)d * kL;
  float4 acc = make_float4(0.f, 0.f, 0.f, 0.f);
  for (int s0 = s_begin; s0 < s_end; s0 += CS) {
    hs[tid] = (s0 + tid < kL) ? hb[s0 + tid] : 0.f;
#pragma unroll
    for (int i = 0; i < 5; ++i) {
      int idx = tid + i * 256;
      int t = t0 - s0 - (CS - 1) + idx;
      us[idx] = (t >= 0 && t < kL) ? (float)ub[t] : 0.f;
    }
    __syncthreads();
    const int send = min(CS, ((s_end - s0) + 3) & ~3);
    float4 hi4 = *(const float4*)&us[4 * tid + 256];
    for (int ss = 0; ss < send; ss += 4) {
      float4 lo4 = *(const float4*)&us[4 * tid + 252 - ss];
      float4 h4  = *(const float4*)&hs[ss];
      acc.x += h4.x * lo4.w; acc.y += h4.x * hi4.x; acc.z += h4.x * hi4.y; acc.w += h4.x * hi4.z;
      acc.x += h4.y * lo4.z; acc.y += h4.y * lo4.w; acc.z += h4.y * hi4.x; acc.w += h4.y * hi4.y;
      acc.x += h4.z * lo4.y; acc.y += h4.z * lo4.z; acc.z += h4.z * lo4.w; acc.w += h4.z * hi4.x;
      acc.x += h4.w * lo4.x; acc.y += h4.w * lo4.y; acc.z += h4.w * lo4.z; acc.w += h4.w * lo4.w;
      hi4 = lo4;
    }
    __syncthreads();
  }
  float* yp = &y[((size_t)b * kD + d) * kL + t0 + 4 * tid];
  if (smax <= SC) {
    // sole writer for this tile (only sc==0 reaches here)
    *(float4*)yp = acc;
  } else {
    atomicAdd(yp + 0, acc.x);
    atomicAdd(yp + 1, acc.y);
    atomicAdd(yp + 2, acc.z);
    atomicAdd(yp + 3, acc.w);
  }
}

// ---------------- K5: gate + transpose  g16[b,t,d] = silu(q16[b,t,d]) * y[b,d,t] ----------------
__global__ __launch_bounds__(256) void gate_transpose(
    const f16* __restrict__ q, const float* __restrict__ y,
    f16* __restrict__ g) {
  __shared__ float ys[32][33];
  const int b  = blockIdx.z;
  const int t0 = blockIdx.x * 32;
  const int d0 = blockIdx.y * 32;
  const int tx = threadIdx.x;
  const int ty = threadIdx.y;
#pragma unroll
  for (int i = 0; i < 4; ++i) {
    int dd = ty + 8 * i;
    ys[dd][tx] = y[((size_t)b * kD + d0 + dd) * kL + t0 + tx];
  }
  __syncthreads();
  const f16* qb = q + (size_t)b * kL * kD;
#pragma unroll
  for (int i = 0; i < 4; ++i) {
    int t = t0 + ty + 8 * i;
    int d = d0 + tx;
    float qv = (float)qb[(size_t)t * kD + d];
    float sq = qv / (1.0f + expf(-qv));
    g[((size_t)b * kL + t) * kD + d] = (f16)(sq * ys[tx][ty + 8 * i]);
  }
}

}  // namespace

extern "C" void kernel_launch(void* const* d_in, const int* in_sizes, int n_in,
                              void* d_out, int out_size, void* d_ws, size_t ws_size,
                              hipStream_t stream) {
  const float* x          = (const float*)d_in[0];
  const float* in_proj_w  = (const float*)d_in[1];
  const float* sck_w      = (const float*)d_in[2];
  const float* sck_b      = (const float*)d_in[3];
  const float* scv_w      = (const float*)d_in[4];
  const float* scv_b      = (const float*)d_in[5];
  const float* mlp_w1     = (const float*)d_in[6];
  const float* mlp_b1     = (const float*)d_in[7];
  const float* mlp_w2     = (const float*)d_in[8];
  const float* mlp_b2     = (const float*)d_in[9];
  const float* mlp_w3     = (const float*)d_in[10];
  const float* mlp_b3     = (const float*)d_in[11];
  const float* log_decay  = (const float*)d_in[12];
  const float* out_proj_w = (const float*)d_in[13];
  float* out = (float*)d_out;

  // workspace layout (bytes), total ~155.7 MB
  char* base = (char*)d_ws;
  const size_t S1 = 25165824;   // q16  [B][L][D] fp16
  const size_t S2 = 50331648;   // kv16 [B][L][2D] fp16  -> later y [B][D][L] fp32
  const size_t S3 = 25165824;   // u16  [B][D][L] fp16
  const size_t S4 = 25165824;   // x16  [B][L][D] fp16   -> later g16
  const size_t S5 = 25165824;   // hfd  [D][L] fp32
  f16*   q16   = (f16*)base;
  f16*   kv16  = (f16*)(base + S1);
  float* y     = (float*)(base + S1);
  f16*   u16   = (f16*)(base + S1 + S2);
  f16*   x16   = (f16*)(base + S1 + S2 + S3);
  f16*   g16   = x16;
  float* hfd   = (float*)(base + S1 + S2 + S3 + S4);
  f16*   w16in = (f16*)(base + S1 + S2 + S3 + S4 + S5);
  f16*   w16out= w16in + (size_t)3 * kD * kD;

  // K0: fp32 -> fp16 conversions
  {
    int n1 = kB * kL * kD;
    int n2 = 3 * kD * kD;
    int n3 = kD * kD;
    cvt_f32_f16<<<(n1 / 8 + 255) / 256, 256, 0, stream>>>(x, x16, n1);
    cvt_f32_f16<<<(n2 / 8 + 255) / 256, 256, 0, stream>>>(in_proj_w, w16in, n2);
    cvt_f32_f16<<<(n3 / 8 + 255) / 256, 256, 0, stream>>>(out_proj_w, w16out, n3);
  }

  // K1: {q16, kv16} = x16 @ w16in^T  (M=16384, N=2304, K=768)
  hgemm_qkv<<<dim3(18, 128), 256, 0, stream>>>(x16, w16in, q16, kv16, kB * kL);

  // K2: u16[b,d,t] = conv_k * conv_v
  dwconv_mul<<<dim3(kL / 32, kD / 32, kB), dim3(32, 8), 0, stream>>>(
      kv16, sck_w, sck_b, scv_w, scv_b, u16);

  // zero y (kv16 is dead after K2; y overlays it). Async memset is capture-legal.
  hipMemsetAsync(y, 0, (size_t)kB * kD * kL * sizeof(float), stream);

  // K3: filter hfd[d][t]
  hyena_filter<<<dim3(kL / 32), 256, 0, stream>>>(
      mlp_w1, mlp_b1, mlp_w2, mlp_b2, mlp_w3, mlp_b3, log_decay, hfd);

  // K4: y[b,d,t] += causal conv(u16, hfd), s-parallel
  long_conv<<<dim3(kL / CT, kD, kB * NSC), 256, 0, stream>>>(u16, hfd, log_decay, y);

  // K5: g16[b,t,d] = silu(q16) * y
  gate_transpose<<<dim3(kL / 32, kD / 32, kB), dim3(32, 8), 0, stream>>>(q16, y, g16);

  // K6: out = g16 @ w16out^T  (M=16384, N=768, K=768)
  hgemm_f32out<<<dim3(6, 128), 256, 0, stream>>>(g16, w16out, out, kB * kL, kD);
}

// Round 6
// 414.833 us; speedup vs baseline: 3.8884x; 1.0139x over previous
//
#include <hip/hip_runtime.h>
#include <math.h>

namespace {

constexpr int kB  = 2;
constexpr int kL  = 8192;
constexpr int kD  = 768;

typedef _Float16 f16;
typedef __attribute__((ext_vector_type(8))) _Float16 f16x8;
typedef __attribute__((ext_vector_type(4))) float f32x4;

__device__ __forceinline__ void gload_lds16(const f16* g, f16* l) {
  __builtin_amdgcn_global_load_lds(
      (__attribute__((address_space(1))) void*)(g),
      (__attribute__((address_space(3))) void*)(l), 16, 0, 0);
}

// ---------------- K0: fp32 -> fp16 conversion ----------------
__global__ __launch_bounds__(256) void cvt_f32_f16(
    const float* __restrict__ s, f16* __restrict__ d, int n) {
  int t = blockIdx.x * 256 + threadIdx.x;
  int i = t * 8;
  if (i >= n) return;
  float4 a = *(const float4*)(s + i);
  float4 b = *(const float4*)(s + i + 4);
  f16x8 v;
  v[0] = (f16)a.x; v[1] = (f16)a.y; v[2] = (f16)a.z; v[3] = (f16)a.w;
  v[4] = (f16)b.x; v[5] = (f16)b.y; v[6] = (f16)b.z; v[7] = (f16)b.w;
  *(f16x8*)(d + i) = v;
}

// ---------------- K1: qkv projection (fp16 MFMA), split outputs ----------------
__global__ __launch_bounds__(256) void hgemm_qkv(
    const f16* __restrict__ A, const f16* __restrict__ W,
    f16* __restrict__ q16, f16* __restrict__ kv16, int M) {
  constexpr int K = 768;
  __shared__ f16 As[128 * 32];
  __shared__ f16 Bs[128 * 32];
  const int tid = threadIdx.x;
  const int bm = blockIdx.y, bn = blockIdx.x;
  const int lane = tid & 63;
  const int wv = tid >> 6;
  const int wr = wv >> 1, wc = wv & 1;
  const int fr = lane & 15, fq = lane >> 4;
  const int srow = tid >> 2;
  const int scol = (tid & 3) * 8;
  const f16* Ab = A + (size_t)bm * 128 * K;
  const f16* Wb = W + (size_t)bn * 128 * K;
  f32x4 acc[4][4];
#pragma unroll
  for (int m = 0; m < 4; ++m)
#pragma unroll
    for (int n = 0; n < 4; ++n)
#pragma unroll
      for (int j = 0; j < 4; ++j) acc[m][n][j] = 0.f;

  for (int k0 = 0; k0 < K; k0 += 32) {
#pragma unroll
    for (int i = 0; i < 2; ++i) {
      gload_lds16(Ab + (size_t)(i * 64 + srow) * K + k0 + scol, As + i * 2048 + wv * 512);
      gload_lds16(Wb + (size_t)(i * 64 + srow) * K + k0 + scol, Bs + i * 2048 + wv * 512);
    }
    __syncthreads();
    f16x8 af[4], bf[4];
#pragma unroll
    for (int m = 0; m < 4; ++m)
      af[m] = *(const f16x8*)&As[(wr * 64 + m * 16 + fr) * 32 + fq * 8];
#pragma unroll
    for (int n = 0; n < 4; ++n)
      bf[n] = *(const f16x8*)&Bs[(wc * 64 + n * 16 + fr) * 32 + fq * 8];
#pragma unroll
    for (int m = 0; m < 4; ++m)
#pragma unroll
      for (int n = 0; n < 4; ++n)
        acc[m][n] = __builtin_amdgcn_mfma_f32_16x16x32_f16(af[m], bf[n], acc[m][n], 0, 0, 0);
    __syncthreads();
  }
#pragma unroll
  for (int m = 0; m < 4; ++m) {
    int grow = bm * 128 + wr * 64 + m * 16 + fq * 4;
#pragma unroll
    for (int n = 0; n < 4; ++n) {
      int gcol = bn * 128 + wc * 64 + n * 16 + fr;
      f16* dst;
      int ldc, col;
      if (gcol < 768) { dst = q16; ldc = 768; col = gcol; }
      else            { dst = kv16; ldc = 1536; col = gcol - 768; }
#pragma unroll
      for (int j = 0; j < 4; ++j)
        dst[(size_t)(grow + j) * ldc + col] = (f16)acc[m][n][j];
    }
  }
}

// ---------------- K6: out = g16 @ w16out^T (fp16 MFMA, fp32 out) ----------------
__global__ __launch_bounds__(256) void hgemm_f32out(
    const f16* __restrict__ A, const f16* __restrict__ W,
    float* __restrict__ C, int M, int N) {
  constexpr int K = 768;
  __shared__ f16 As[128 * 32];
  __shared__ f16 Bs[128 * 32];
  const int tid = threadIdx.x;
  const int bm = blockIdx.y, bn = blockIdx.x;
  const int lane = tid & 63;
  const int wv = tid >> 6;
  const int wr = wv >> 1, wc = wv & 1;
  const int fr = lane & 15, fq = lane >> 4;
  const int srow = tid >> 2;
  const int scol = (tid & 3) * 8;
  const f16* Ab = A + (size_t)bm * 128 * K;
  const f16* Wb = W + (size_t)bn * 128 * K;
  f32x4 acc[4][4];
#pragma unroll
  for (int m = 0; m < 4; ++m)
#pragma unroll
    for (int n = 0; n < 4; ++n)
#pragma unroll
      for (int j = 0; j < 4; ++j) acc[m][n][j] = 0.f;

  for (int k0 = 0; k0 < K; k0 += 32) {
#pragma unroll
    for (int i = 0; i < 2; ++i) {
      gload_lds16(Ab + (size_t)(i * 64 + srow) * K + k0 + scol, As + i * 2048 + wv * 512);
      gload_lds16(Wb + (size_t)(i * 64 + srow) * K + k0 + scol, Bs + i * 2048 + wv * 512);
    }
    __syncthreads();
    f16x8 af[4], bf[4];
#pragma unroll
    for (int m = 0; m < 4; ++m)
      af[m] = *(const f16x8*)&As[(wr * 64 + m * 16 + fr) * 32 + fq * 8];
#pragma unroll
    for (int n = 0; n < 4; ++n)
      bf[n] = *(const f16x8*)&Bs[(wc * 64 + n * 16 + fr) * 32 + fq * 8];
#pragma unroll
    for (int m = 0; m < 4; ++m)
#pragma unroll
      for (int n = 0; n < 4; ++n)
        acc[m][n] = __builtin_amdgcn_mfma_f32_16x16x32_f16(af[m], bf[n], acc[m][n], 0, 0, 0);
    __syncthreads();
  }
#pragma unroll
  for (int m = 0; m < 4; ++m) {
    int grow = bm * 128 + wr * 64 + m * 16 + fq * 4;
#pragma unroll
    for (int n = 0; n < 4; ++n) {
      int gcol = bn * 128 + wc * 64 + n * 16 + fr;
#pragma unroll
      for (int j = 0; j < 4; ++j)
        C[(size_t)(grow + j) * N + gcol] = acc[m][n][j];
    }
  }
}

// ---------------- K2: depthwise causal conv(k=3) on k,v + product, transpose ----------------
__global__ __launch_bounds__(256) void dwconv_mul(
    const f16* __restrict__ kv,
    const float* __restrict__ sck_w, const float* __restrict__ sck_b,
    const float* __restrict__ scv_w, const float* __restrict__ scv_b,
    f16* __restrict__ u) {
  __shared__ float ks[34][33];
  __shared__ float vs[34][33];
  const int b  = blockIdx.z;
  const int d0 = blockIdx.y * 32;
  const int t0 = blockIdx.x * 32;
  const int tx = threadIdx.x;
  const int ty = threadIdx.y;
  const f16* base = kv + (size_t)b * kL * (2 * kD);
  for (int r = ty; r < 34; r += 8) {
    int t = t0 - 2 + r;
    float kk = 0.f, vv = 0.f;
    if (t >= 0) {
      kk = (float)base[(size_t)t * (2 * kD) + d0 + tx];
      vv = (float)base[(size_t)t * (2 * kD) + kD + d0 + tx];
    }
    ks[r][tx] = kk;
    vs[r][tx] = vv;
  }
  __syncthreads();
#pragma unroll
  for (int i = 0; i < 4; ++i) {
    int dd = ty + 8 * i;
    int d = d0 + dd;
    float kw0 = sck_w[d * 3 + 0], kw1 = sck_w[d * 3 + 1], kw2 = sck_w[d * 3 + 2];
    float vw0 = scv_w[d * 3 + 0], vw1 = scv_w[d * 3 + 1], vw2 = scv_w[d * 3 + 2];
    float kc = kw0 * ks[tx][dd] + kw1 * ks[tx + 1][dd] + kw2 * ks[tx + 2][dd] + sck_b[d];
    float vc = vw0 * vs[tx][dd] + vw1 * vs[tx + 1][dd] + vw2 * vs[tx + 2][dd] + scv_b[d];
    u[((size_t)b * kD + d) * kL + t0 + tx] = (f16)(kc * vc);
  }
}

// ---------------- K3: hyena filter  hfd[d][t] (fp32) ----------------
__global__ __launch_bounds__(256) void hyena_filter(
    const float* __restrict__ w1, const float* __restrict__ b1,
    const float* __restrict__ w2, const float* __restrict__ b2,
    const float* __restrict__ w3, const float* __restrict__ b3,
    const float* __restrict__ log_decay, float* __restrict__ hfd) {
  __shared__ float w1s[64 * 65];
  __shared__ float w2s[64 * 65];
  __shared__ float h2s[32][64];
  __shared__ float pe[64];
  __shared__ float h1v[64];
  const int tid = threadIdx.x;
  for (int i = tid; i < 64 * 64; i += 256) {
    w1s[(i >> 6) * 65 + (i & 63)] = w1[i];
    w2s[(i >> 6) * 65 + (i & 63)] = w2[i];
  }
  __syncthreads();
  const int tbase = blockIdx.x * 32;
  const float TWO_PI = 6.28318530717958647692f;
  for (int tt = 0; tt < 32; ++tt) {
    int t = tbase + tt;
    float tn = (float)t / 8191.0f;
    if (tid < 64) {
      float f = TWO_PI * (float)((tid & 31) + 1);
      pe[tid] = (tid < 32) ? sinf(tn * f) : cosf(tn * f);
    }
    __syncthreads();
    if (tid < 64) {
      float s = b1[tid];
      for (int j = 0; j < 64; ++j) s += pe[j] * w1s[tid * 65 + j];
      h1v[tid] = s / (1.0f + expf(-s));
    }
    __syncthreads();
    if (tid < 64) {
      float s = b2[tid];
      for (int j = 0; j < 64; ++j) s += h1v[j] * w2s[tid * 65 + j];
      h2s[tt][tid] = s / (1.0f + expf(-s));
    }
    __syncthreads();
  }
  for (int d = tid; d < kD; d += 256) {
    float a = fabsf(log_decay[d]);
    float bb = b3[d];
    float acc[32];
#pragma unroll
    for (int tt = 0; tt < 32; ++tt) acc[tt] = bb;
    for (int j = 0; j < 64; ++j) {
      float w = w3[d * 64 + j];
#pragma unroll
      for (int tt = 0; tt < 32; ++tt) acc[tt] += h2s[tt][j] * w;
    }
    for (int tt = 0; tt < 32; ++tt) {
      int t = tbase + tt;
      hfd[(size_t)d * kL + t] = acc[tt] * expf(-a * (float)t);
    }
  }
}

// ---------------- K4a: build compact worklist ----------------
// item = d | tile<<10 | sc<<13 | smax<<16   (smax = min(Td, (tile+1)*1024))
__global__ __launch_bounds__(768) void build_worklist(
    const float* __restrict__ log_decay, int* __restrict__ items,
    int* __restrict__ n_items) {
  __shared__ int cnt[768];
  const int d = threadIdx.x;
  float a = fabsf(log_decay[d]);
  int Td = (a * (float)kL <= 20.0f) ? kL : ((int)(20.0f / a) + 1);
  int smax_t[8];
  int c = 0;
#pragma unroll
  for (int tile = 0; tile < 8; ++tile) {
    int smax = min(Td, (tile + 1) * 1024);
    smax_t[tile] = smax;
    c += (smax + 1023) >> 10;
  }
  cnt[d] = c;
  __syncthreads();
  for (int off = 1; off < 768; off <<= 1) {
    int v = (d >= off) ? cnt[d - off] : 0;
    __syncthreads();
    cnt[d] += v;
    __syncthreads();
  }
  int base = cnt[d] - c;  // exclusive prefix
#pragma unroll
  for (int tile = 0; tile < 8; ++tile) {
    int nsc = (smax_t[tile] + 1023) >> 10;
    for (int sc = 0; sc < nsc; ++sc)
      items[base++] = d | (tile << 10) | (sc << 13) | (smax_t[tile] << 16);
  }
  if (d == 767) n_items[0] = cnt[767];
}

// ---------------- K4b: causal long conv over worklist (both batches/item) ----------------
constexpr int CT = 1024;
constexpr int CS = 256;
constexpr int SC = 1024;
__global__ __launch_bounds__(256) void long_conv_wl(
    const f16* __restrict__ u, const float* __restrict__ hfd,
    const int* __restrict__ items, const int* __restrict__ n_items,
    float* __restrict__ y) {
  __shared__ __align__(16) float hs[CS];
  __shared__ __align__(16) float us0[1288];
  __shared__ __align__(16) float us1[1288];
  const int tid = threadIdx.x;
  const int n = n_items[0];
  for (int it = blockIdx.x; it < n; it += gridDim.x) {
    const int item = items[it];
    const int d    = item & 1023;
    const int tile = (item >> 10) & 7;
    const int sc   = (item >> 13) & 7;
    const int smax = item >> 16;
    const int t0 = tile << 10;
    const int s_begin = sc << 10;
    const int s_end = min(s_begin + SC, smax);
    const f16* ub0 = u + (size_t)d * kL;           // b=0
    const f16* ub1 = u + (size_t)(kD + d) * kL;    // b=1
    const float* hb = hfd + (size_t)d * kL;
    float4 acc0 = make_float4(0.f, 0.f, 0.f, 0.f);
    float4 acc1 = make_float4(0.f, 0.f, 0.f, 0.f);
    for (int s0 = s_begin; s0 < s_end; s0 += CS) {
      hs[tid] = hb[s0 + tid];
      const int t_al = t0 - s0 - 256;  // multiple of 256 (8-aligned)
      // us[ix] <-> t = t0 - s0 - 255 + ix ; vector j covers ix = 8j-1..8j+6
      if (tid < 160) {
        int g = t_al + 8 * tid;
        int bi = 8 * tid - 1;
        if (g >= 0) {
          f16x8 v = *(const f16x8*)(ub0 + g);
#pragma unroll
          for (int e = 0; e < 8; ++e) { int ix = bi + e; if (ix >= 0) us0[ix] = (float)v[e]; }
        } else {
#pragma unroll
          for (int e = 0; e < 8; ++e) { int ix = bi + e; if (ix >= 0) us0[ix] = 0.f; }
        }
      }
      if (tid >= 96) {
        int j = tid - 96;
        int g = t_al + 8 * j;
        int bi = 8 * j - 1;
        if (g >= 0) {
          f16x8 v = *(const f16x8*)(ub1 + g);
#pragma unroll
          for (int e = 0; e < 8; ++e) { int ix = bi + e; if (ix >= 0) us1[ix] = (float)v[e]; }
        } else {
#pragma unroll
          for (int e = 0; e < 8; ++e) { int ix = bi + e; if (ix >= 0) us1[ix] = 0.f; }
        }
      }
      __syncthreads();
      const int send = min(CS, ((s_end - s0) + 3) & ~3);
      float4 hi0 = *(const float4*)&us0[4 * tid + 256];
      float4 hi1 = *(const float4*)&us1[4 * tid + 256];
      for (int ss = 0; ss < send; ss += 4) {
        float4 h4  = *(const float4*)&hs[ss];
        float4 lo0 = *(const float4*)&us0[4 * tid + 252 - ss];
        acc0.x += h4.x * lo0.w; acc0.y += h4.x * hi0.x; acc0.z += h4.x * hi0.y; acc0.w += h4.x * hi0.z;
        acc0.x += h4.y * lo0.z; acc0.y += h4.y * lo0.w; acc0.z += h4.y * hi0.x; acc0.w += h4.y * hi0.y;
        acc0.x += h4.z * lo0.y; acc0.y += h4.z * lo0.z; acc0.z += h4.z * lo0.w; acc0.w += h4.z * hi0.x;
        acc0.x += h4.w * lo0.x; acc0.y += h4.w * lo0.y; acc0.z += h4.w * lo0.z; acc0.w += h4.w * lo0.w;
        hi0 = lo0;
        float4 lo1 = *(const float4*)&us1[4 * tid + 252 - ss];
        acc1.x += h4.x * lo1.w; acc1.y += h4.x * hi1.x; acc1.z += h4.x * hi1.y; acc1.w += h4.x * hi1.z;
        acc1.x += h4.y * lo1.z; acc1.y += h4.y * lo1.w; acc1.z += h4.y * hi1.x; acc1.w += h4.y * hi1.y;
        acc1.x += h4.z * lo1.y; acc1.y += h4.z * lo1.z; acc1.z += h4.z * lo1.w; acc1.w += h4.z * hi1.x;
        acc1.x += h4.w * lo1.x; acc1.y += h4.w * lo1.y; acc1.z += h4.w * lo1.z; acc1.w += h4.w * lo1.w;
        hi1 = lo1;
      }
      __syncthreads();
    }
    float* y0 = &y[(size_t)d * kL + t0 + 4 * tid];
    float* y1 = &y[(size_t)(kD + d) * kL + t0 + 4 * tid];
    if (smax <= SC) {  // sole writer (nsc == 1 for this tile)
      *(float4*)y0 = acc0;
      *(float4*)y1 = acc1;
    } else {
      atomicAdd(y0 + 0, acc0.x); atomicAdd(y0 + 1, acc0.y);
      atomicAdd(y0 + 2, acc0.z); atomicAdd(y0 + 3, acc0.w);
      atomicAdd(y1 + 0, acc1.x); atomicAdd(y1 + 1, acc1.y);
      atomicAdd(y1 + 2, acc1.z); atomicAdd(y1 + 3, acc1.w);
    }
  }
}

// ---------------- K5: gate + transpose  g16[b,t,d] = silu(q16[b,t,d]) * y[b,d,t] ----------------
__global__ __launch_bounds__(256) void gate_transpose(
    const f16* __restrict__ q, const float* __restrict__ y,
    f16* __restrict__ g) {
  __shared__ float ys[32][33];
  const int b  = blockIdx.z;
  const int t0 = blockIdx.x * 32;
  const int d0 = blockIdx.y * 32;
  const int tx = threadIdx.x;
  const int ty = threadIdx.y;
#pragma unroll
  for (int i = 0; i < 4; ++i) {
    int dd = ty + 8 * i;
    ys[dd][tx] = y[((size_t)b * kD + d0 + dd) * kL + t0 + tx];
  }
  __syncthreads();
  const f16* qb = q + (size_t)b * kL * kD;
#pragma unroll
  for (int i = 0; i < 4; ++i) {
    int t = t0 + ty + 8 * i;
    int d = d0 + tx;
    float qv = (float)qb[(size_t)t * kD + d];
    float sq = qv / (1.0f + expf(-qv));
    g[((size_t)b * kL + t) * kD + d] = (f16)(sq * ys[tx][ty + 8 * i]);
  }
}

}  // namespace

extern "C" void kernel_launch(void* const* d_in, const int* in_sizes, int n_in,
                              void* d_out, int out_size, void* d_ws, size_t ws_size,
                              hipStream_t stream) {
  const float* x          = (const float*)d_in[0];
  const float* in_proj_w  = (const float*)d_in[1];
  const float* sck_w      = (const float*)d_in[2];
  const float* sck_b      = (const float*)d_in[3];
  const float* scv_w      = (const float*)d_in[4];
  const float* scv_b      = (const float*)d_in[5];
  const float* mlp_w1     = (const float*)d_in[6];
  const float* mlp_b1     = (const float*)d_in[7];
  const float* mlp_w2     = (const float*)d_in[8];
  const float* mlp_b2     = (const float*)d_in[9];
  const float* mlp_w3     = (const float*)d_in[10];
  const float* mlp_b3     = (const float*)d_in[11];
  const float* log_decay  = (const float*)d_in[12];
  const float* out_proj_w = (const float*)d_in[13];
  float* out = (float*)d_out;

  // workspace layout (bytes), ~160 MB total
  char* base = (char*)d_ws;
  const size_t S1 = 25165824;   // q16  [B][L][D] fp16
  const size_t S2 = 50331648;   // kv16 [B][L][2D] fp16  -> later y [B][D][L] fp32
  const size_t S3 = 25165824;   // u16  [B][D][L] fp16
  const size_t S4 = 25165824;   // x16  [B][L][D] fp16   -> later g16
  const size_t S5 = 25165824;   // hfd  [D][L] fp32
  f16*   q16   = (f16*)base;
  f16*   kv16  = (f16*)(base + S1);
  float* y     = (float*)(base + S1);
  f16*   u16   = (f16*)(base + S1 + S2);
  f16*   x16   = (f16*)(base + S1 + S2 + S3);
  f16*   g16   = x16;
  float* hfd   = (float*)(base + S1 + S2 + S3 + S4);
  f16*   w16in = (f16*)(base + S1 + S2 + S3 + S4 + S5);
  f16*   w16out= w16in + (size_t)3 * kD * kD;
  int*   items = (int*)(w16out + (size_t)kD * kD);   // up to 64K ints
  int*   n_items = items + 65536;

  // K0: fp32 -> fp16 conversions
  {
    int n1 = kB * kL * kD;
    int n2 = 3 * kD * kD;
    int n3 = kD * kD;
    cvt_f32_f16<<<(n1 / 8 + 255) / 256, 256, 0, stream>>>(x, x16, n1);
    cvt_f32_f16<<<(n2 / 8 + 255) / 256, 256, 0, stream>>>(in_proj_w, w16in, n2);
    cvt_f32_f16<<<(n3 / 8 + 255) / 256, 256, 0, stream>>>(out_proj_w, w16out, n3);
  }

  // K1: {q16, kv16} = x16 @ w16in^T  (M=16384, N=2304, K=768)
  hgemm_qkv<<<dim3(18, 128), 256, 0, stream>>>(x16, w16in, q16, kv16, kB * kL);

  // K2: u16[b,d,t] = conv_k * conv_v
  dwconv_mul<<<dim3(kL / 32, kD / 32, kB), dim3(32, 8), 0, stream>>>(
      kv16, sck_w, sck_b, scv_w, scv_b, u16);

  // zero y (kv16 dead after K2; y overlays it)
  hipMemsetAsync(y, 0, (size_t)kB * kD * kL * sizeof(float), stream);

  // K3: filter hfd[d][t]
  hyena_filter<<<dim3(kL / 32), 256, 0, stream>>>(
      mlp_w1, mlp_b1, mlp_w2, mlp_b2, mlp_w3, mlp_b3, log_decay, hfd);

  // K4a: compact worklist
  build_worklist<<<1, 768, 0, stream>>>(log_decay, items, n_items);

  // K4b: y[b,d,t] += causal conv(u16, hfd) over worklist (both b per item)
  long_conv_wl<<<2048, 256, 0, stream>>>(u16, hfd, items, n_items, y);

  // K5: g16[b,t,d] = silu(q16) * y
  gate_transpose<<<dim3(kL / 32, kD / 32, kB), dim3(32, 8), 0, stream>>>(q16, y, g16);

  // K6: out = g16 @ w16out^T  (M=16384, N=768, K=768)
  hgemm_f32out<<<dim3(6, 128), 256, 0, stream>>>(g16, w16out, out, kB * kL, kD);
}